// Round 1
// 794.643 us; speedup vs baseline: 1.0418x; 1.0418x over previous
//
#include <hip/hip_runtime.h>
#include <cstdint>
#include <cstddef>

#define T_TOK 512
#define H_DIM 2048
#define E_NUM 32
#define K_TOP 4
#define F_DIM 1024
#define NZ_DIM 16
#define ZH_DIM 512

typedef __attribute__((ext_vector_type(8))) short bf16x8;
typedef __attribute__((ext_vector_type(4))) float f32x4;
typedef __attribute__((ext_vector_type(4))) float f4v;
typedef __attribute__((ext_vector_type(4))) unsigned short us4;
typedef __attribute__((ext_vector_type(8))) unsigned short us8;

__device__ __forceinline__ unsigned short f2bf(float f) {
  union { float f; unsigned int u; } c; c.f = f;
  unsigned int u = c.u;
  return (unsigned short)((u + 0x7fffu + ((u >> 16) & 1u)) >> 16);  // RNE
}

__device__ __forceinline__ float silu_f(float v) { return v / (1.f + __expf(-v)); }

// ---------------------------------------------------------------------------
// x fp32 -> bf16 prepass: [512][2048] -> 2 MB, done once (was redone per f-tile)
// ---------------------------------------------------------------------------
__global__ __launch_bounds__(256) void x2bf_kernel(const float* __restrict__ x,
                                                   unsigned short* __restrict__ xb)
{
  const int i = (blockIdx.x * 256 + threadIdx.x) * 8;
  const f4v a = *(const f4v*)(x + i);
  const f4v b = *(const f4v*)(x + i + 4);
  us8 o;
  #pragma unroll
  for (int j = 0; j < 4; j++) { o[j] = f2bf(a[j]); o[4 + j] = f2bf(b[j]); }
  *(us8*)(xb + i) = o;
}

// ---------------------------------------------------------------------------
// zh = silu(x @ z_w1^T + z_b1)  [512, 512] fp32 (selection-critical).
// Same arithmetic as before; adds register prefetch of next k-tile (bit-identical).
// ---------------------------------------------------------------------------
__global__ __launch_bounds__(256) void zh_gemm_kernel(
    const float* __restrict__ x, const float* __restrict__ z_w1,
    const float* __restrict__ z_b1, float* __restrict__ zh)
{
  __shared__ float xs[32][33];
  __shared__ float ws[32][33];
  const int m0 = blockIdx.x * 32, n0 = blockIdx.y * 32;
  const int tid = threadIdx.x;
  const int tm = tid >> 4, tn = tid & 15;
  const int r = tid >> 3, c4 = (tid & 7) << 2;
  float a00 = 0.f, a01 = 0.f, a10 = 0.f, a11 = 0.f;
  f4v xv = *(const f4v*)(x + (size_t)(m0 + r) * H_DIM + c4);
  f4v wv = *(const f4v*)(z_w1 + (size_t)(n0 + r) * H_DIM + c4);
  for (int k0 = 0; k0 < H_DIM; k0 += 32) {
    xs[r][c4 + 0] = xv[0]; xs[r][c4 + 1] = xv[1]; xs[r][c4 + 2] = xv[2]; xs[r][c4 + 3] = xv[3];
    ws[r][c4 + 0] = wv[0]; ws[r][c4 + 1] = wv[1]; ws[r][c4 + 2] = wv[2]; ws[r][c4 + 3] = wv[3];
    __syncthreads();
    if (k0 + 32 < H_DIM) {
      xv = *(const f4v*)(x + (size_t)(m0 + r) * H_DIM + k0 + 32 + c4);
      wv = *(const f4v*)(z_w1 + (size_t)(n0 + r) * H_DIM + k0 + 32 + c4);
    }
    #pragma unroll
    for (int k = 0; k < 32; k++) {
      float x0 = xs[tm * 2][k], x1 = xs[tm * 2 + 1][k];
      float w0 = ws[tn * 2][k], w1 = ws[tn * 2 + 1][k];
      a00 += x0 * w0; a01 += x0 * w1; a10 += x1 * w0; a11 += x1 * w1;
    }
    __syncthreads();
  }
  const float b0 = z_b1[n0 + tn * 2], b1 = z_b1[n0 + tn * 2 + 1];
  float* o0 = zh + (size_t)(m0 + tm * 2) * ZH_DIM + n0 + tn * 2;
  float* o1 = o0 + ZH_DIM;
  o0[0] = silu_f(a00 + b0); o0[1] = silu_f(a01 + b1);
  o1[0] = silu_f(a10 + b0); o1[1] = silu_f(a11 + b1);
}

// ---------------------------------------------------------------------------
// Routing: UNCHANGED (fp32 selection path; any reassociation risks expert flips)
// ---------------------------------------------------------------------------
__global__ __launch_bounds__(256) void routing_kernel(
    const float* __restrict__ x, const float* __restrict__ u,
    const float* __restrict__ gate_w, const float* __restrict__ zh,
    const float* __restrict__ z_w2, const float* __restrict__ z_b2,
    const float* __restrict__ Umat, int* __restrict__ cnt,
    int* __restrict__ a_tok, float* __restrict__ a_wgt, int* __restrict__ a_slot)
{
  const int t = blockIdx.x;
  const int tid = threadIdx.x;
  __shared__ float xs[H_DIM];
  __shared__ float red[256];
  __shared__ float zl[NZ_DIM];
  __shared__ float lg[E_NUM];
  __shared__ float prob[E_NUM];
  __shared__ int zi_s;
  __shared__ float mx_s;

  for (int i = tid; i < H_DIM / 4; i += 256)
    ((float4*)xs)[i] = ((const float4*)(x + (size_t)t * H_DIM))[i];

  {
    const int j = tid & 15, part = tid >> 4;
    const float* zrow = zh + (size_t)t * ZH_DIM + part * 32;
    const float* wrow = z_w2 + (size_t)j * ZH_DIM + part * 32;
    float s = 0.f;
    #pragma unroll
    for (int i = 0; i < 32; i++) s += zrow[i] * wrow[i];
    red[tid] = s;
  }
  __syncthreads();
  if (tid < NZ_DIM) {
    float acc = z_b2[tid];
    #pragma unroll
    for (int p = 0; p < 16; p++) acc += red[p * 16 + tid];
    float uu = u[(size_t)t * NZ_DIM + tid];
    zl[tid] = acc - logf(-logf(uu));
  }
  __syncthreads();

  {
    const int ee = tid & 31, part = tid >> 5;
    const float* grow = gate_w + (size_t)ee * H_DIM + part * 256;
    const float* xp = xs + part * 256;
    float s = 0.f;
    for (int i = 0; i < 256; i++) s += xp[i] * grow[i];
    red[tid] = s;
  }
  __syncthreads();
  if (tid == 0) {
    int zi = 0; float best = zl[0];
    for (int j = 1; j < NZ_DIM; j++) if (zl[j] > best) { best = zl[j]; zi = j; }
    zi_s = zi;
  }
  __syncthreads();
  if (tid < E_NUM) {
    float acc = 0.f;
    #pragma unroll
    for (int p = 0; p < 8; p++) acc += red[p * 32 + tid];
    lg[tid] = acc + Umat[(size_t)zi_s * E_NUM + tid];
  }
  __syncthreads();
  if (tid == 0) {
    float mx = lg[0];
    for (int i = 1; i < E_NUM; i++) mx = fmaxf(mx, lg[i]);
    mx_s = mx;
  }
  __syncthreads();
  if (tid < E_NUM) prob[tid] = expf(lg[tid] - mx_s);
  __syncthreads();
  if (tid == 0) {
    float sum = 0.f;
    for (int i = 0; i < E_NUM; i++) sum += prob[i];
    const float inv = 1.f / sum;
    unsigned int used = 0;
    for (int k = 0; k < K_TOP; k++) {
      int be = 0; float bv = -1.f;
      for (int i = 0; i < E_NUM; i++)
        if (!((used >> i) & 1u) && prob[i] > bv) { bv = prob[i]; be = i; }
      used |= 1u << be;
      const int pos = atomicAdd(&cnt[be], 1);
      a_tok[be * T_TOK + pos]  = t;
      a_wgt[be * T_TOK + pos]  = bv * inv;
      a_slot[be * T_TOK + pos] = t * K_TOP + k;
    }
  }
}

// ---------------------------------------------------------------------------
// GEMM1 v2: per (f-tile 64, expert, m-tile 128).
//  - A (x_bf16) per-lane direct global fragment loads (L2-resident, no LDS)
//  - B (Wg/Wu fp32) reg-staged 1-tile lookahead, BK=64, 4x4 in-reg transpose,
//    ds_write_b128 into XOR-swizzled [f][k] tiles (conflict-optimal), dbuf,
//    ONE barrier per K-step.
// ---------------------------------------------------------------------------
__global__ __launch_bounds__(256) void expert_gemm1(
    const unsigned short* __restrict__ xb, const float* __restrict__ Wg,
    const float* __restrict__ Wu, const int* __restrict__ cnt,
    const int* __restrict__ a_tok, const float* __restrict__ a_wgt,
    const int* __restrict__ a_slot, unsigned short* __restrict__ act)
{
  const int e = blockIdx.y;
  const int f0 = blockIdx.x * 64;
  const int m_base = blockIdx.z * 128;
  const int n_e = cnt[e];
  if (m_base >= n_e) return;
  const int rows = min(128, n_e - m_base);

  // [buf][mat][f-row * 64 + swizzled k] ; rows are 128B, chunk = 16B = 8 bf16
  __shared__ unsigned short wlds[2][2][64 * 64];
  __shared__ int   tok_s[128];
  __shared__ float wgt_s[128];
  __shared__ int   slot_s[128];

  const int tid = threadIdx.x;
  if (tid < 128) {
    int tk = 0, sl = 0; float w = 0.f;
    if (tid < rows) {
      tk = a_tok[e * T_TOK + m_base + tid];
      w  = a_wgt[e * T_TOK + m_base + tid];
      sl = a_slot[e * T_TOK + m_base + tid];
    }
    tok_s[tid] = tk; wgt_s[tid] = w; slot_s[tid] = sl;
  }

  // staging roles: 128 threads per matrix; thread owns f rows sf..sf+3, k chunk ski (k = ski*8..+7)
  const int mat = tid >> 7;
  const int s   = tid & 127;
  const int sf  = (s & 15) * 4;
  const int ski = s >> 4;                 // 0..7
  const size_t wbase = (size_t)e * (size_t)H_DIM * F_DIM;
  const float* wsrc = (mat ? Wu : Wg) + wbase + (size_t)(ski * 8) * F_DIM + f0 + sf;

  f4v v[8];
  #pragma unroll
  for (int r = 0; r < 8; r++) v[r] = *(const f4v*)(wsrc + (size_t)r * F_DIM);
  {
    unsigned short* dst = &wlds[0][mat][0];
    #pragma unroll
    for (int j = 0; j < 4; j++) {
      const int row = sf + j;
      us8 w;
      #pragma unroll
      for (int r = 0; r < 8; r++) w[r] = f2bf(v[r][j]);
      *(us8*)(dst + row * 64 + (ski ^ (row & 7)) * 8) = w;
    }
  }
  __syncthreads();

  const int wave = tid >> 6, lane = tid & 63;
  const int lm = lane & 15, quad = lane >> 4;
  const int tokA0 = tok_s[wave * 32 + lm];
  const int tokA1 = tok_s[wave * 32 + 16 + lm];
  const unsigned short* xr0 = xb + (size_t)tokA0 * H_DIM + quad * 8;
  const unsigned short* xr1 = xb + (size_t)tokA1 * H_DIM + quad * 8;

  f32x4 accg[2][4], accu[2][4];
  const f32x4 zero4 = {0.f, 0.f, 0.f, 0.f};
  #pragma unroll
  for (int i = 0; i < 2; i++)
    #pragma unroll
    for (int j = 0; j < 4; j++) { accg[i][j] = zero4; accu[i][j] = zero4; }

  const int NT = H_DIM / 64;  // 32
  #pragma unroll 2
  for (int t = 0; t < NT; t++) {
    const int cur = t & 1;
    if (t + 1 < NT) {           // issue next-tile weight loads FIRST (in flight across compute)
      const float* nsrc = wsrc + (size_t)((t + 1) * 64) * F_DIM;
      #pragma unroll
      for (int r = 0; r < 8; r++) v[r] = *(const f4v*)(nsrc + (size_t)r * F_DIM);
    }
    const unsigned short* wg_b = &wlds[cur][0][0];
    const unsigned short* wu_b = &wlds[cur][1][0];
    const int kbase = t * 64;
    #pragma unroll
    for (int kk = 0; kk < 2; kk++) {
      const bf16x8 a0 = *(const bf16x8*)(xr0 + kbase + kk * 32);
      const bf16x8 a1 = *(const bf16x8*)(xr1 + kbase + kk * 32);
      #pragma unroll
      for (int ns = 0; ns < 4; ns++) {
        const int row = ns * 16 + lm;
        const int chunk = (((kk << 2) + quad) ^ (row & 7)) * 8;
        const bf16x8 bg = *(const bf16x8*)(wg_b + row * 64 + chunk);
        const bf16x8 bu = *(const bf16x8*)(wu_b + row * 64 + chunk);
        accg[0][ns] = __builtin_amdgcn_mfma_f32_16x16x32_bf16(a0, bg, accg[0][ns], 0, 0, 0);
        accg[1][ns] = __builtin_amdgcn_mfma_f32_16x16x32_bf16(a1, bg, accg[1][ns], 0, 0, 0);
        accu[0][ns] = __builtin_amdgcn_mfma_f32_16x16x32_bf16(a0, bu, accu[0][ns], 0, 0, 0);
        accu[1][ns] = __builtin_amdgcn_mfma_f32_16x16x32_bf16(a1, bu, accu[1][ns], 0, 0, 0);
      }
    }
    if (t + 1 < NT) {           // write NEXT buffer (no conflict with current readers)
      unsigned short* dst = &wlds[cur ^ 1][mat][0];
      #pragma unroll
      for (int j = 0; j < 4; j++) {
        const int row = sf + j;
        us8 w;
        #pragma unroll
        for (int r = 0; r < 8; r++) w[r] = f2bf(v[r][j]);
        *(us8*)(dst + row * 64 + (ski ^ (row & 7)) * 8) = w;
      }
    }
    __syncthreads();            // single barrier per K-step
  }

  #pragma unroll
  for (int ms = 0; ms < 2; ms++) {
    #pragma unroll
    for (int r = 0; r < 4; r++) {
      const int m = wave * 32 + ms * 16 + quad * 4 + r;
      if (m < rows) {
        const float w = wgt_s[m];
        unsigned short* orow = act + (size_t)slot_s[m] * F_DIM + f0 + lm;
        #pragma unroll
        for (int ns = 0; ns < 4; ns++) {
          const float g = accg[ms][ns][r];
          const float uu = accu[ms][ns][r];
          orow[ns * 16] = f2bf(silu_f(g) * uu * w);
        }
      }
    }
  }
}

// ---------------------------------------------------------------------------
// GEMM2 v2: per (h-tile 64, expert, m-tile 128). A = act (bf16, direct global
// frags); B = Wd fp32 reg-staged BK=128, swizzled [h][k] dbuf, 1 barrier/step.
// ---------------------------------------------------------------------------
__global__ __launch_bounds__(256) void expert_gemm2(
    const unsigned short* __restrict__ act, const float* __restrict__ Wd,
    const int* __restrict__ cnt, const int* __restrict__ a_tok,
    const int* __restrict__ a_slot, float* __restrict__ out)
{
  const int e = blockIdx.y;
  const int h0 = blockIdx.x * 64;
  const int m_base = blockIdx.z * 128;
  const int n_e = cnt[e];
  if (m_base >= n_e) return;
  const int rows = min(128, n_e - m_base);

  __shared__ unsigned short wlds[2][64 * 128];  // [buf][h-row * 128 + swizzled k], 256B rows
  __shared__ int tok_s[128];
  __shared__ int slot_s[128];

  const int tid = threadIdx.x;
  if (tid < 128) {
    int tk = 0, sl = 0;
    if (tid < rows) {
      tk = a_tok[e * T_TOK + m_base + tid];
      sl = a_slot[e * T_TOK + m_base + tid];
    }
    tok_s[tid] = tk; slot_s[tid] = sl;
  }

  const int sf  = (tid & 15) * 4;
  const int ski = tid >> 4;               // 0..15
  const size_t wbase = (size_t)e * (size_t)F_DIM * H_DIM;
  const float* wsrc = Wd + wbase + (size_t)(ski * 8) * H_DIM + h0 + sf;

  f4v v[8];
  #pragma unroll
  for (int r = 0; r < 8; r++) v[r] = *(const f4v*)(wsrc + (size_t)r * H_DIM);
  {
    unsigned short* dst = &wlds[0][0];
    #pragma unroll
    for (int j = 0; j < 4; j++) {
      const int row = sf + j;
      us8 w;
      #pragma unroll
      for (int r = 0; r < 8; r++) w[r] = f2bf(v[r][j]);
      *(us8*)(dst + row * 128 + (ski ^ (row & 15)) * 8) = w;
    }
  }
  __syncthreads();

  const int wave = tid >> 6, lane = tid & 63;
  const int lm = lane & 15, quad = lane >> 4;
  const int slotA0 = slot_s[wave * 32 + lm];
  const int slotA1 = slot_s[wave * 32 + 16 + lm];
  const unsigned short* ar0 = act + (size_t)slotA0 * F_DIM + quad * 8;
  const unsigned short* ar1 = act + (size_t)slotA1 * F_DIM + quad * 8;

  f32x4 acc[2][4];
  const f32x4 zero4 = {0.f, 0.f, 0.f, 0.f};
  #pragma unroll
  for (int i = 0; i < 2; i++)
    #pragma unroll
    for (int j = 0; j < 4; j++) acc[i][j] = zero4;

  const int NT = F_DIM / 128;  // 8
  #pragma unroll 2
  for (int t = 0; t < NT; t++) {
    const int cur = t & 1;
    if (t + 1 < NT) {
      const float* nsrc = wsrc + (size_t)((t + 1) * 128) * H_DIM;
      #pragma unroll
      for (int r = 0; r < 8; r++) v[r] = *(const f4v*)(nsrc + (size_t)r * H_DIM);
    }
    const unsigned short* wb = &wlds[cur][0];
    const int kbase = t * 128;
    #pragma unroll
    for (int kk = 0; kk < 4; kk++) {
      const bf16x8 a0 = *(const bf16x8*)(ar0 + kbase + kk * 32);
      const bf16x8 a1 = *(const bf16x8*)(ar1 + kbase + kk * 32);
      #pragma unroll
      for (int ns = 0; ns < 4; ns++) {
        const int row = ns * 16 + lm;
        const int chunk = (((kk << 2) + quad) ^ (row & 15)) * 8;
        const bf16x8 b = *(const bf16x8*)(wb + row * 128 + chunk);
        acc[0][ns] = __builtin_amdgcn_mfma_f32_16x16x32_bf16(a0, b, acc[0][ns], 0, 0, 0);
        acc[1][ns] = __builtin_amdgcn_mfma_f32_16x16x32_bf16(a1, b, acc[1][ns], 0, 0, 0);
      }
    }
    if (t + 1 < NT) {
      unsigned short* dst = &wlds[cur ^ 1][0];
      #pragma unroll
      for (int j = 0; j < 4; j++) {
        const int row = sf + j;
        us8 w;
        #pragma unroll
        for (int r = 0; r < 8; r++) w[r] = f2bf(v[r][j]);
        *(us8*)(dst + row * 128 + (ski ^ (row & 15)) * 8) = w;
      }
    }
    __syncthreads();
  }

  #pragma unroll
  for (int ms = 0; ms < 2; ms++) {
    #pragma unroll
    for (int r = 0; r < 4; r++) {
      const int m = wave * 32 + ms * 16 + quad * 4 + r;
      if (m < rows) {
        float* orow = out + (size_t)tok_s[m] * H_DIM + h0 + lm;
        #pragma unroll
        for (int ns = 0; ns < 4; ns++) atomicAdd(orow + ns * 16, acc[ms][ns][r]);
      }
    }
  }
}

// ---------------------------------------------------------------------------
extern "C" void kernel_launch(void* const* d_in, const int* in_sizes, int n_in,
                              void* d_out, int out_size, void* d_ws, size_t ws_size,
                              hipStream_t stream)
{
  const float* x      = (const float*)d_in[0];
  const float* u      = (const float*)d_in[1];
  const float* gate_w = (const float*)d_in[2];
  const float* z_w1   = (const float*)d_in[3];
  const float* z_b1   = (const float*)d_in[4];
  const float* z_w2   = (const float*)d_in[5];
  const float* z_b2   = (const float*)d_in[6];
  const float* Umat   = (const float*)d_in[7];
  const float* Wg     = (const float*)d_in[8];
  const float* Wu     = (const float*)d_in[9];
  const float* Wd     = (const float*)d_in[10];
  float* out = (float*)d_out;

  char* ws = (char*)d_ws;
  int*   cnt    = (int*)(ws);                                  // 32 ints
  int*   a_tok  = (int*)(ws + 256);                            // 32*512 ints
  float* a_wgt  = (float*)(ws + 256 + 65536);
  int*   a_slot = (int*)(ws + 256 + 2 * 65536);
  float* zh     = (float*)(ws + 256 + 3 * 65536);              // 512*512 fp32 (1 MB)
  unsigned short* act = (unsigned short*)(ws + 256 + 3 * 65536 + 1048576);      // 2048*1024 bf16 (4 MB)
  unsigned short* xb  = (unsigned short*)(ws + 256 + 3 * 65536 + 1048576 + 4194304); // 512*2048 bf16 (2 MB)

  hipMemsetAsync(cnt, 0, E_NUM * sizeof(int), stream);
  hipMemsetAsync(out, 0, (size_t)T_TOK * H_DIM * sizeof(float), stream);

  x2bf_kernel<<<dim3(512), 256, 0, stream>>>(x, xb);
  zh_gemm_kernel<<<dim3(16, 16), 256, 0, stream>>>(x, z_w1, z_b1, zh);
  routing_kernel<<<dim3(T_TOK), 256, 0, stream>>>(x, u, gate_w, zh, z_w2, z_b2, Umat,
                                                  cnt, a_tok, a_wgt, a_slot);
  expert_gemm1<<<dim3(16, 32, 4), 256, 0, stream>>>(
      xb, Wg, Wu, cnt, a_tok, a_wgt, a_slot, act);
  expert_gemm2<<<dim3(32, 32, 4), 256, 0, stream>>>(
      act, Wd, cnt, a_tok, a_slot, out);
}